// Round 4
// baseline (400.886 us; speedup 1.0000x reference)
//
#include <hip/hip_runtime.h>
#include <hip/hip_bf16.h>

typedef __bf16 bf16;
typedef __attribute__((ext_vector_type(8))) __bf16 bf16x8;
typedef __attribute__((ext_vector_type(4))) __bf16 bf16x4;
typedef __attribute__((ext_vector_type(4))) float f32x4;

#define D_MODEL 1024
#define NHEAD 16
#define DK 64
#define BB 4
#define SS 2048
#define MM 8192
#define KK 2048
#define NN 3072

#define LDP 72
#define QSCALE 0.18033688011112042f  // 0.125 * log2(e)

__device__ __forceinline__ void glds16(const bf16* g, bf16* s) {
    __builtin_amdgcn_global_load_lds(
        (const __attribute__((address_space(1))) void*)g,
        (__attribute__((address_space(3))) void*)s, 16, 0, 0);
}

// ---------------------------------------------------------------------------
// Tile-packed XOR-swizzled layout: tile=128 rows x 64 cols, chunk c of row mi
// at slot mi*8 + (c^(mi&7)); tiles [row_tile][k_tile].
// ---------------------------------------------------------------------------
__device__ __forceinline__ void pack_chunk(const float* __restrict__ src,
                                           bf16* __restrict__ dst,
                                           int row_off, int col_off, int idx) {
    int m = idx >> 7;        // source row (1024 cols = 128 chunks)
    int cl = idx & 127;
    const float4* s4 = (const float4*)&src[((size_t)m << 10) + cl * 8];
    float4 v0 = s4[0], v1 = s4[1];
    bf16x8 o;
    o[0]=(bf16)v0.x; o[1]=(bf16)v0.y; o[2]=(bf16)v0.z; o[3]=(bf16)v0.w;
    o[4]=(bf16)v1.x; o[5]=(bf16)v1.y; o[6]=(bf16)v1.z; o[7]=(bf16)v1.w;
    int r = row_off + m;
    int k = col_off + cl * 8;
    int mi = r & 127, mt = r >> 7;
    int c = (k >> 3) & 7, kt = k >> 6;
    int slot = mi * 8 + (c ^ (mi & 7));
    *(bf16x8*)&dst[(((((size_t)mt * 32 + kt) << 10) + slot) << 3)] = o;
}

__global__ void pack_x(const float* __restrict__ Xs, const float* __restrict__ Xt,
                       bf16* __restrict__ dst) {
    int i = blockIdx.x * 256 + threadIdx.x;     // 2 * 2^20 chunks
    int sel = i >> 20;
    int idx = i & 1048575;
    pack_chunk(sel ? Xt : Xs, dst, 0, sel ? 1024 : 0, idx);
}

__global__ void pack_w(const float* __restrict__ Wqs, const float* __restrict__ Wqt,
                       const float* __restrict__ Wks, const float* __restrict__ Wkt,
                       const float* __restrict__ Wvs, const float* __restrict__ Wvt,
                       const float* __restrict__ bqs, const float* __restrict__ bqt,
                       const float* __restrict__ bks, const float* __restrict__ bkt,
                       const float* __restrict__ bvs, const float* __restrict__ bvt,
                       bf16* __restrict__ dst, float* __restrict__ biasc) {
    if (blockIdx.x == 3072) {   // bias tail block
        for (int n = threadIdx.x; n < NN; n += 256) {
            int g = n >> 10, c = n & 1023;
            const float* a = (g == 0) ? bqs : ((g == 1) ? bks : bvs);
            const float* b = (g == 0) ? bqt : ((g == 1) ? bkt : bvt);
            biasc[n] = a[c] + b[c];
        }
        return;
    }
    int i = blockIdx.x * 256 + threadIdx.x;     // 6 * 2^17 chunks
    int gi = i >> 17;
    int idx = i & 131071;
    const float* src = (gi == 0) ? Wqs : (gi == 1) ? Wqt : (gi == 2) ? Wks
                     : (gi == 3) ? Wkt : (gi == 4) ? Wvs : Wvt;
    pack_chunk(src, dst, (gi >> 1) * 1024, (gi & 1) * 1024, idx);
}

// ---------------------------------------------------------------------------
// QKV GEMM (m97-style) — unchanged from R3 (plateau).
// ---------------------------------------------------------------------------
__global__ __launch_bounds__(256) void gemm_qkv(
    const bf16* __restrict__ Xp, const bf16* __restrict__ Wp,
    const float* __restrict__ biasc,
    bf16* __restrict__ Qb, bf16* __restrict__ Kb, bf16* __restrict__ Vt) {
    __shared__ __align__(16) bf16 sA[128 * 64];
    __shared__ __align__(16) bf16 sB[128 * 64];

    const int m0 = blockIdx.x * 128, n0 = blockIdx.y * 128;
    const int t = threadIdx.x, lane = t & 63, w = t >> 6;
    const int quad = lane >> 4, l16 = lane & 15, swz = l16 & 7;
    const int wm = (w >> 1) * 64, wn = (w & 1) * 64;

    f32x4 acc[4][4] = {};

    for (int ktI = 0; ktI < 32; ktI++) {
        const bf16* Ab = Xp + (((size_t)blockIdx.x * 32 + ktI) << 13);
        const bf16* Bb = Wp + (((size_t)blockIdx.y * 32 + ktI) << 13);
#pragma unroll
        for (int j = 0; j < 4; j++) {
            int u = (w * 4 + j) * 64 + lane;
            glds16(Ab + (size_t)u * 8, &sA[(w * 4 + j) * 512]);
            glds16(Bb + (size_t)u * 8, &sB[(w * 4 + j) * 512]);
        }
        __syncthreads();
#pragma unroll
        for (int kb = 0; kb < 2; kb++) {
            bf16x8 af[4], bfr[4];
#pragma unroll
            for (int mi = 0; mi < 4; mi++)
                af[mi] = *(const bf16x8*)&sA[(wm + mi * 16 + l16) * 64 + (((kb * 4 + quad) ^ swz) * 8)];
#pragma unroll
            for (int ni = 0; ni < 4; ni++)
                bfr[ni] = *(const bf16x8*)&sB[(wn + ni * 16 + l16) * 64 + (((kb * 4 + quad) ^ swz) * 8)];
#pragma unroll
            for (int mi = 0; mi < 4; mi++)
#pragma unroll
                for (int ni = 0; ni < 4; ni++)
                    acc[mi][ni] = __builtin_amdgcn_mfma_f32_16x16x32_bf16(
                        af[mi], bfr[ni], acc[mi][ni], 0, 0, 0);
        }
        __syncthreads();
    }

    const int g = n0 >> 10;
    for (int mi = 0; mi < 4; mi++) {
        int mbase = m0 + wm + mi * 16 + quad * 4;
        for (int ni = 0; ni < 4; ni++) {
            int n = n0 + wn + ni * 16 + l16;
            float bias = biasc[n];
            int c = n & 1023, h = c >> 6, d = c & 63;
            for (int r = 0; r < 4; r++) {
                int m = mbase + r;
                int b = m >> 11, s = m & 2047;
                size_t bh = (size_t)(b * NHEAD + h);
                float v = acc[mi][ni][r] + bias;
                if (g == 0)
                    Qb[(bh * SS + s) * DK + d] = (bf16)(v * QSCALE);
                else if (g == 1)
                    Kb[(bh * SS + s) * DK + d] = (bf16)v;
                else
                    Vt[(bh * DK + d) * SS + s] = (bf16)v;
            }
        }
    }
}

// ---------------------------------------------------------------------------
// Flash attention: 256 q/block (64 q/wave, f=0..3), 64-key tiles.
// kf/vf hoisted to registers once per tile -> LDS reads amortized over 4 f's.
// No-max softmax (|scores*log2e| <~ 18, exp2-safe), deferred denominator.
// ---------------------------------------------------------------------------
__global__ __launch_bounds__(256) void attn(
    const bf16* __restrict__ Qb, const bf16* __restrict__ Kb,
    const bf16* __restrict__ Vt, float* __restrict__ out) {
    __shared__ __align__(16) bf16 sK[64 * 64];
    __shared__ __align__(16) bf16 sV[64 * 64];
    __shared__ __align__(16) bf16 sP[4][64 * LDP];

    const int q0 = blockIdx.x * 256;
    const int bh = blockIdx.y;
    const int t = threadIdx.x;
    const int lane = t & 63, w = t >> 6;
    const int quad = lane >> 4, l16 = lane & 15, swz = l16 & 7;
    const int b = bh >> 4, h = bh & 15;

    const bf16* Qp = Qb + ((size_t)bh * SS + q0 + w * 64) * DK;
    bf16x8 qf[4][2];
#pragma unroll
    for (int f = 0; f < 4; f++)
#pragma unroll
        for (int kb = 0; kb < 2; kb++)
            qf[f][kb] = *(const bf16x8*)&Qp[(f * 16 + l16) * DK + kb * 32 + quad * 8];

    f32x4 o[4][4] = {};
    float lsum[4] = {0.f, 0.f, 0.f, 0.f};

    const bf16* Kp = Kb + (size_t)bh * SS * DK;
    const bf16* Vp = Vt + (size_t)bh * DK * SS;

    for (int kt = 0; kt < SS; kt += 64) {
#pragma unroll
        for (int j = 0; j < 2; j++) {
            int u = (w * 2 + j) * 64 + lane;
            int row = u >> 3;
            int cc = (u & 7) ^ (row & 7);
            glds16(Kp + (size_t)(kt + row) * DK + cc * 8, &sK[(w * 2 + j) * 512]);
            glds16(Vp + (size_t)row * SS + kt + cc * 8, &sV[(w * 2 + j) * 512]);
        }
        __syncthreads();

        // K fragments once per tile (shared across the 4 q-frags)
        bf16x8 kf[2][4];
#pragma unroll
        for (int kb = 0; kb < 2; kb++)
#pragma unroll
            for (int ki = 0; ki < 4; ki++)
                kf[kb][ki] = *(const bf16x8*)&sK[(ki * 16 + l16) * 64 + (((kb * 4 + quad) ^ swz) * 8)];

#pragma unroll
        for (int f = 0; f < 4; f++) {
            // S^T = K * Q^T : lane holds keys ki*16+quad*4+r for q-col l16
            f32x4 st[4] = {};
#pragma unroll
            for (int kb = 0; kb < 2; kb++)
#pragma unroll
                for (int ki = 0; ki < 4; ki++)
                    st[ki] = __builtin_amdgcn_mfma_f32_16x16x32_bf16(
                        kf[kb][ki], qf[f][kb], st[ki], 0, 0, 0);

            float ls = 0.f;
#pragma unroll
            for (int ki = 0; ki < 4; ki++) {
                float p0 = __builtin_amdgcn_exp2f(st[ki][0]);
                float p1 = __builtin_amdgcn_exp2f(st[ki][1]);
                float p2 = __builtin_amdgcn_exp2f(st[ki][2]);
                float p3 = __builtin_amdgcn_exp2f(st[ki][3]);
                ls += (p0 + p1) + (p2 + p3);
                bf16x4 pk;
                pk[0] = (bf16)p0; pk[1] = (bf16)p1; pk[2] = (bf16)p2; pk[3] = (bf16)p3;
                *(bf16x4*)&sP[w][(f * 16 + l16) * LDP + ki * 16 + quad * 4] = pk;
            }
            lsum[f] += ls;
        }

        // V fragments once per tile
        bf16x8 vf[2][4];
#pragma unroll
        for (int kb = 0; kb < 2; kb++)
#pragma unroll
            for (int ni = 0; ni < 4; ni++)
                vf[kb][ni] = *(const bf16x8*)&sV[(ni * 16 + l16) * 64 + (((kb * 4 + quad) ^ swz) * 8)];

        // O += P*V  (sP wave-private; in-wave lgkmcnt covers write->read)
#pragma unroll
        for (int f = 0; f < 4; f++)
#pragma unroll
            for (int kb = 0; kb < 2; kb++) {
                bf16x8 af = *(const bf16x8*)&sP[w][(f * 16 + l16) * LDP + kb * 32 + quad * 8];
#pragma unroll
                for (int ni = 0; ni < 4; ni++)
                    o[f][ni] = __builtin_amdgcn_mfma_f32_16x16x32_bf16(
                        af, vf[kb][ni], o[f][ni], 0, 0, 0);
            }
        __syncthreads();
    }

#pragma unroll
    for (int f = 0; f < 4; f++) {
        lsum[f] += __shfl_xor(lsum[f], 16);
        lsum[f] += __shfl_xor(lsum[f], 32);
    }

    float* op = out + ((size_t)(b * SS + q0 + w * 64)) * D_MODEL + h * DK;
#pragma unroll
    for (int f = 0; f < 4; f++)
#pragma unroll
        for (int r = 0; r < 4; r++) {
            float linv = 1.0f / __shfl(lsum[f], quad * 4 + r);
#pragma unroll
            for (int ni = 0; ni < 4; ni++)
                op[(f * 16 + quad * 4 + r) * D_MODEL + ni * 16 + l16] = o[f][ni][r] * linv;
        }
}

extern "C" void kernel_launch(void* const* d_in, const int* in_sizes, int n_in,
                              void* d_out, int out_size, void* d_ws, size_t ws_size,
                              hipStream_t stream) {
    const float* Xs   = (const float*)d_in[0];
    const float* Xt   = (const float*)d_in[1];
    const float* Wqs  = (const float*)d_in[2];
    const float* bqs  = (const float*)d_in[3];
    const float* Wqt  = (const float*)d_in[4];
    const float* bqt  = (const float*)d_in[5];
    const float* Wks  = (const float*)d_in[6];
    const float* bks  = (const float*)d_in[7];
    const float* Wkt  = (const float*)d_in[8];
    const float* bkt  = (const float*)d_in[9];
    const float* Wvs  = (const float*)d_in[10];
    const float* bvs  = (const float*)d_in[11];
    const float* Wvt  = (const float*)d_in[12];
    const float* bvt  = (const float*)d_in[13];
    float* out = (float*)d_out;

    char* ws = (char*)d_ws;
    bf16*  Xp    = (bf16*)(ws);                 // 32 MB packed-swizzled
    bf16*  Wp    = (bf16*)(ws + 33554432);      // 12 MB packed-swizzled
    float* biasc = (float*)(ws + 46137344);     // 12 KB
    bf16*  Qb    = (bf16*)(ws + 46149632);      // 16 MB
    bf16*  Kb    = (bf16*)(ws + 62926848);      // 16 MB
    bf16*  Vt    = (bf16*)(ws + 79704064);      // 16 MB

    pack_x<<<8192, 256, 0, stream>>>(Xs, Xt, Xp);
    pack_w<<<3073, 256, 0, stream>>>(Wqs, Wqt, Wks, Wkt, Wvs, Wvt,
                                     bqs, bqt, bks, bkt, bvs, bvt, Wp, biasc);

    gemm_qkv<<<dim3(MM / 128, NN / 128), 256, 0, stream>>>(Xp, Wp, biasc, Qb, Kb, Vt);

    attn<<<dim3(SS / 256, BB * NHEAD), 256, 0, stream>>>(Qb, Kb, Vt, out);
}

// Round 5
// 365.934 us; speedup vs baseline: 1.0955x; 1.0955x over previous
//
#include <hip/hip_runtime.h>
#include <hip/hip_bf16.h>

typedef __bf16 bf16;
typedef __attribute__((ext_vector_type(8))) __bf16 bf16x8;
typedef __attribute__((ext_vector_type(4))) __bf16 bf16x4;
typedef __attribute__((ext_vector_type(4))) float f32x4;

#define D_MODEL 1024
#define NHEAD 16
#define DK 64
#define BB 4
#define SS 2048
#define MM 8192
#define KK 2048
#define NN 3072

#define LDP 72
#define QSCALE 0.18033688011112042f  // 0.125 * log2(e)

__device__ __forceinline__ void glds16(const bf16* g, bf16* s) {
    __builtin_amdgcn_global_load_lds(
        (const __attribute__((address_space(1))) void*)g,
        (__attribute__((address_space(3))) void*)s, 16, 0, 0);
}

// ---------------------------------------------------------------------------
// Tile-packed XOR-swizzled layout: tile=128 rows x 64 cols, chunk c of row mi
// at slot mi*8 + (c^(mi&7)); tiles [row_tile][k_tile].
// ---------------------------------------------------------------------------
__device__ __forceinline__ void pack_chunk(const float* __restrict__ src,
                                           bf16* __restrict__ dst,
                                           int row_off, int col_off, int idx) {
    int m = idx >> 7;        // source row (1024 cols = 128 chunks)
    int cl = idx & 127;
    const float4* s4 = (const float4*)&src[((size_t)m << 10) + cl * 8];
    float4 v0 = s4[0], v1 = s4[1];
    bf16x8 o;
    o[0]=(bf16)v0.x; o[1]=(bf16)v0.y; o[2]=(bf16)v0.z; o[3]=(bf16)v0.w;
    o[4]=(bf16)v1.x; o[5]=(bf16)v1.y; o[6]=(bf16)v1.z; o[7]=(bf16)v1.w;
    int r = row_off + m;
    int k = col_off + cl * 8;
    int mi = r & 127, mt = r >> 7;
    int c = (k >> 3) & 7, kt = k >> 6;
    int slot = mi * 8 + (c ^ (mi & 7));
    *(bf16x8*)&dst[(((((size_t)mt * 32 + kt) << 10) + slot) << 3)] = o;
}

// One kernel packs X (2*2^20 chunks), W (6*2^17 chunks), bias (tail block).
__global__ void pack_all(const float* __restrict__ Xs, const float* __restrict__ Xt,
                         const float* __restrict__ Wqs, const float* __restrict__ Wqt,
                         const float* __restrict__ Wks, const float* __restrict__ Wkt,
                         const float* __restrict__ Wvs, const float* __restrict__ Wvt,
                         const float* __restrict__ bqs, const float* __restrict__ bqt,
                         const float* __restrict__ bks, const float* __restrict__ bkt,
                         const float* __restrict__ bvs, const float* __restrict__ bvt,
                         bf16* __restrict__ Xp, bf16* __restrict__ Wp,
                         float* __restrict__ biasc) {
    int blk = blockIdx.x;
    if (blk < 8192) {                      // X: 2 * 1,048,576 chunks
        int i = blk * 256 + threadIdx.x;
        int sel = i >> 20;
        int idx = i & 1048575;
        pack_chunk(sel ? Xt : Xs, Xp, 0, sel ? 1024 : 0, idx);
        return;
    }
    if (blk < 11264) {                     // W: 6 * 131,072 chunks
        int i = (blk - 8192) * 256 + threadIdx.x;
        int gi = i >> 17;
        int idx = i & 131071;
        const float* src = (gi == 0) ? Wqs : (gi == 1) ? Wqt : (gi == 2) ? Wks
                         : (gi == 3) ? Wkt : (gi == 4) ? Wvs : Wvt;
        pack_chunk(src, Wp, (gi >> 1) * 1024, (gi & 1) * 1024, idx);
        return;
    }
    for (int n = threadIdx.x; n < NN; n += 256) {   // bias tail
        int g = n >> 10, c = n & 1023;
        const float* a = (g == 0) ? bqs : ((g == 1) ? bks : bvs);
        const float* b = (g == 0) ? bqt : ((g == 1) ? bkt : bvt);
        biasc[n] = a[c] + b[c];
    }
}

// ---------------------------------------------------------------------------
// QKV GEMM (m97-style) — unchanged (plateau: 131 us, 0 conflicts).
// ---------------------------------------------------------------------------
__global__ __launch_bounds__(256) void gemm_qkv(
    const bf16* __restrict__ Xp, const bf16* __restrict__ Wp,
    const float* __restrict__ biasc,
    bf16* __restrict__ Qb, bf16* __restrict__ Kb, bf16* __restrict__ Vt) {
    __shared__ __align__(16) bf16 sA[128 * 64];
    __shared__ __align__(16) bf16 sB[128 * 64];

    const int m0 = blockIdx.x * 128, n0 = blockIdx.y * 128;
    const int t = threadIdx.x, lane = t & 63, w = t >> 6;
    const int quad = lane >> 4, l16 = lane & 15, swz = l16 & 7;
    const int wm = (w >> 1) * 64, wn = (w & 1) * 64;

    f32x4 acc[4][4] = {};

    for (int ktI = 0; ktI < 32; ktI++) {
        const bf16* Ab = Xp + (((size_t)blockIdx.x * 32 + ktI) << 13);
        const bf16* Bb = Wp + (((size_t)blockIdx.y * 32 + ktI) << 13);
#pragma unroll
        for (int j = 0; j < 4; j++) {
            int u = (w * 4 + j) * 64 + lane;
            glds16(Ab + (size_t)u * 8, &sA[(w * 4 + j) * 512]);
            glds16(Bb + (size_t)u * 8, &sB[(w * 4 + j) * 512]);
        }
        __syncthreads();
#pragma unroll
        for (int kb = 0; kb < 2; kb++) {
            bf16x8 af[4], bfr[4];
#pragma unroll
            for (int mi = 0; mi < 4; mi++)
                af[mi] = *(const bf16x8*)&sA[(wm + mi * 16 + l16) * 64 + (((kb * 4 + quad) ^ swz) * 8)];
#pragma unroll
            for (int ni = 0; ni < 4; ni++)
                bfr[ni] = *(const bf16x8*)&sB[(wn + ni * 16 + l16) * 64 + (((kb * 4 + quad) ^ swz) * 8)];
#pragma unroll
            for (int mi = 0; mi < 4; mi++)
#pragma unroll
                for (int ni = 0; ni < 4; ni++)
                    acc[mi][ni] = __builtin_amdgcn_mfma_f32_16x16x32_bf16(
                        af[mi], bfr[ni], acc[mi][ni], 0, 0, 0);
        }
        __syncthreads();
    }

    const int g = n0 >> 10;
    for (int mi = 0; mi < 4; mi++) {
        int mbase = m0 + wm + mi * 16 + quad * 4;
        for (int ni = 0; ni < 4; ni++) {
            int n = n0 + wn + ni * 16 + l16;
            float bias = biasc[n];
            int c = n & 1023, h = c >> 6, d = c & 63;
            for (int r = 0; r < 4; r++) {
                int m = mbase + r;
                int b = m >> 11, s = m & 2047;
                size_t bh = (size_t)(b * NHEAD + h);
                float v = acc[mi][ni][r] + bias;
                if (g == 0)
                    Qb[(bh * SS + s) * DK + d] = (bf16)(v * QSCALE);
                else if (g == 1)
                    Kb[(bh * SS + s) * DK + d] = (bf16)v;
                else
                    Vt[(bh * DK + d) * SS + s] = (bf16)v;
            }
        }
    }
}

// ---------------------------------------------------------------------------
// Flash attention — R3 config (proven): 128 q/block, 32 q/wave (f=0..1),
// 64-key tiles, no-max softmax, deferred denominator, S^T = K*Q^T.
// NEW: XCD-aware block swizzle — XCD k (= linear_id % 8) serves bh in
// {8k..8k+7}, so one XCD's K/V working set = 8 * 512KB = 4MB = its L2.
// ---------------------------------------------------------------------------
__global__ __launch_bounds__(256) void attn(
    const bf16* __restrict__ Qb, const bf16* __restrict__ Kb,
    const bf16* __restrict__ Vt, float* __restrict__ out) {
    __shared__ __align__(16) bf16 sK[64 * 64];
    __shared__ __align__(16) bf16 sV[64 * 64];
    __shared__ __align__(16) bf16 sP[4][32 * LDP];

    // linear dispatch id -> (q-tile, bh) with bh low-3-bits = id%8 (XCD)
    const int lid = blockIdx.x + gridDim.x * blockIdx.y;   // 0..1023
    const int bh = (lid & 7) * 8 + ((lid >> 3) & 7);       // 0..63
    const int q0 = (lid >> 6) * 128;                       // 0..15 tiles

    const int t = threadIdx.x;
    const int lane = t & 63, w = t >> 6;
    const int quad = lane >> 4, l16 = lane & 15, swz = l16 & 7;
    const int b = bh >> 4, h = bh & 15;

    const bf16* Qp = Qb + ((size_t)bh * SS + q0 + w * 32) * DK;
    bf16x8 qf[2][2];
#pragma unroll
    for (int f = 0; f < 2; f++)
#pragma unroll
        for (int kb = 0; kb < 2; kb++)
            qf[f][kb] = *(const bf16x8*)&Qp[(f * 16 + l16) * DK + kb * 32 + quad * 8];

    f32x4 o[2][4] = {};
    float lsum[2] = {0.f, 0.f};

    const bf16* Kp = Kb + (size_t)bh * SS * DK;
    const bf16* Vp = Vt + (size_t)bh * DK * SS;

    for (int kt = 0; kt < SS; kt += 64) {
#pragma unroll
        for (int j = 0; j < 2; j++) {
            int u = (w * 2 + j) * 64 + lane;
            int row = u >> 3;
            int cc = (u & 7) ^ (row & 7);   // global-side swizzle
            glds16(Kp + (size_t)(kt + row) * DK + cc * 8, &sK[(w * 2 + j) * 512]);
            glds16(Vp + (size_t)row * SS + kt + cc * 8, &sV[(w * 2 + j) * 512]);
        }
        __syncthreads();

        // S^T = K * Q^T : lane holds keys ki*16+quad*4+r for q-col l16
        f32x4 st[2][4] = {};
#pragma unroll
        for (int kb = 0; kb < 2; kb++)
#pragma unroll
            for (int ki = 0; ki < 4; ki++) {
                bf16x8 kf = *(const bf16x8*)&sK[(ki * 16 + l16) * 64 + (((kb * 4 + quad) ^ swz) * 8)];
                st[0][ki] = __builtin_amdgcn_mfma_f32_16x16x32_bf16(kf, qf[0][kb], st[0][ki], 0, 0, 0);
                st[1][ki] = __builtin_amdgcn_mfma_f32_16x16x32_bf16(kf, qf[1][kb], st[1][ki], 0, 0, 0);
            }

        // p = exp2(s); deferred denominator; P -> sP[q][key] packed b64
#pragma unroll
        for (int f = 0; f < 2; f++) {
            float ls = 0.f;
#pragma unroll
            for (int ki = 0; ki < 4; ki++) {
                float p0 = __builtin_amdgcn_exp2f(st[f][ki][0]);
                float p1 = __builtin_amdgcn_exp2f(st[f][ki][1]);
                float p2 = __builtin_amdgcn_exp2f(st[f][ki][2]);
                float p3 = __builtin_amdgcn_exp2f(st[f][ki][3]);
                ls += (p0 + p1) + (p2 + p3);
                bf16x4 pk;
                pk[0] = (bf16)p0; pk[1] = (bf16)p1; pk[2] = (bf16)p2; pk[3] = (bf16)p3;
                *(bf16x4*)&sP[w][(f * 16 + l16) * LDP + ki * 16 + quad * 4] = pk;
            }
            lsum[f] += ls;
        }

        // O += P*V (sP wave-private: in-wave lgkmcnt covers write->read)
#pragma unroll
        for (int kb = 0; kb < 2; kb++) {
            bf16x8 af0 = *(const bf16x8*)&sP[w][(l16) * LDP + kb * 32 + quad * 8];
            bf16x8 af1 = *(const bf16x8*)&sP[w][(16 + l16) * LDP + kb * 32 + quad * 8];
#pragma unroll
            for (int ni = 0; ni < 4; ni++) {
                bf16x8 vf = *(const bf16x8*)&sV[(ni * 16 + l16) * 64 + (((kb * 4 + quad) ^ swz) * 8)];
                o[0][ni] = __builtin_amdgcn_mfma_f32_16x16x32_bf16(af0, vf, o[0][ni], 0, 0, 0);
                o[1][ni] = __builtin_amdgcn_mfma_f32_16x16x32_bf16(af1, vf, o[1][ni], 0, 0, 0);
            }
        }
        __syncthreads();
    }

#pragma unroll
    for (int f = 0; f < 2; f++) {
        lsum[f] += __shfl_xor(lsum[f], 16);
        lsum[f] += __shfl_xor(lsum[f], 32);
    }

    float* op = out + ((size_t)(b * SS + q0 + w * 32)) * D_MODEL + h * DK;
#pragma unroll
    for (int f = 0; f < 2; f++)
#pragma unroll
        for (int r = 0; r < 4; r++) {
            float linv = 1.0f / __shfl(lsum[f], quad * 4 + r);
#pragma unroll
            for (int ni = 0; ni < 4; ni++)
                op[(f * 16 + quad * 4 + r) * D_MODEL + ni * 16 + l16] = o[f][ni][r] * linv;
        }
}

extern "C" void kernel_launch(void* const* d_in, const int* in_sizes, int n_in,
                              void* d_out, int out_size, void* d_ws, size_t ws_size,
                              hipStream_t stream) {
    const float* Xs   = (const float*)d_in[0];
    const float* Xt   = (const float*)d_in[1];
    const float* Wqs  = (const float*)d_in[2];
    const float* bqs  = (const float*)d_in[3];
    const float* Wqt  = (const float*)d_in[4];
    const float* bqt  = (const float*)d_in[5];
    const float* Wks  = (const float*)d_in[6];
    const float* bks  = (const float*)d_in[7];
    const float* Wkt  = (const float*)d_in[8];
    const float* bkt  = (const float*)d_in[9];
    const float* Wvs  = (const float*)d_in[10];
    const float* bvs  = (const float*)d_in[11];
    const float* Wvt  = (const float*)d_in[12];
    const float* bvt  = (const float*)d_in[13];
    float* out = (float*)d_out;

    char* ws = (char*)d_ws;
    bf16*  Xp    = (bf16*)(ws);                 // 32 MB packed-swizzled
    bf16*  Wp    = (bf16*)(ws + 33554432);      // 12 MB packed-swizzled
    float* biasc = (float*)(ws + 46137344);     // 12 KB
    bf16*  Qb    = (bf16*)(ws + 46149632);      // 16 MB
    bf16*  Kb    = (bf16*)(ws + 62926848);      // 16 MB
    bf16*  Vt    = (bf16*)(ws + 79704064);      // 16 MB

    pack_all<<<11265, 256, 0, stream>>>(Xs, Xt, Wqs, Wqt, Wks, Wkt, Wvs, Wvt,
                                        bqs, bqt, bks, bkt, bvs, bvt,
                                        Xp, Wp, biasc);

    gemm_qkv<<<dim3(MM / 128, NN / 128), 256, 0, stream>>>(Xp, Wp, biasc, Qb, Kb, Vt);

    attn<<<dim3(SS / 128, BB * NHEAD), 256, 0, stream>>>(Qb, Kb, Vt, out);
}